// Round 2
// baseline (58.549 us; speedup 1.0000x reference)
//
#include <hip/hip_runtime.h>

#define B_ 4
#define H_ 68
#define W_ 120
#define J_ (H_*W_)            // 8160 cells per batch
#define HF 544
#define WF 960
#define TS 32
#define TXN (WF/TS)           // 30
#define TYN (HF/TS)           // 17
#define NTILE (B_*TXN*TYN)    // 2040
#define CAPMAX 512

// ws layout:
//   float4 cdata[B_*J_]            : 32640*16 = 522240 B
//   int    counts[NTILE]           : 2040*4 = 8160 B
//   int    lists[NTILE*cap]
#define CDATA_BYTES (B_*J_*16)
#define COUNT_BYTES (NTILE*4)

// Phase 0: zero the per-tile counters. hipMemsetAsync graph-captured as a
// fill node cost ~39us/replay (R1 profile: fillBufferAligned, ~0 bytes, 39us);
// a plain 8-block kernel is ~2us.
__global__ __launch_bounds__(256) void pif_zero(int* __restrict__ counts) {
    int i = blockIdx.x * 256 + threadIdx.x;
    if (i < NTILE) counts[i] = 0;
}

// Phase 1: per-cell binning. Each active cell appends its index to all tiles
// within its truncation radius r = sqrt(2*var*ln(conf*1e5)).
__global__ __launch_bounds__(256) void pif_bin(const float* __restrict__ mean,
                                               const float* __restrict__ var,
                                               const float* __restrict__ conf,
                                               float4* __restrict__ cdata,
                                               int* __restrict__ counts,
                                               int* __restrict__ lists,
                                               int cap) {
    int gid = blockIdx.x * 256 + threadIdx.x;
    if (gid >= B_ * J_) return;
    int b = gid / J_;
    int j = gid - b * J_;

    float mx = mean[2 * gid + 0];
    float my = mean[2 * gid + 1];
    float v  = var[gid];
    float cf = conf[gid];
    float iv = 1.0f / (2.0f * v);
    cdata[gid] = make_float4(mx, my, iv, cf);

    if (!(cf > 0.1f)) return;   // thresholded cells contribute exactly 0

    // cut where conf*exp(-d^2 * iv) < 1e-5  ->  d^2 > 2*var*ln(conf*1e5)
    float lc = __logf(cf * 1e5f);           // conf>0.1 -> lc in [9.2, 11.5]
    float r  = sqrtf(fmaxf(2.0f * v * lc, 0.0f));

    int tx0 = max(0,       (int)floorf((mx - r) * (1.0f / TS)));
    int tx1 = min(TXN - 1, (int)floorf((mx + r) * (1.0f / TS)));
    int ty0 = max(0,       (int)floorf((my - r) * (1.0f / TS)));
    int ty1 = min(TYN - 1, (int)floorf((my + r) * (1.0f / TS)));

    for (int ty = ty0; ty <= ty1; ++ty) {
        for (int tx = tx0; tx <= tx1; ++tx) {
            int t = (b * TYN + ty) * TXN + tx;
            int idx = atomicAdd(&counts[t], 1);
            if (idx < cap) lists[(size_t)t * cap + idx] = j;
        }
    }
}

// Phase 2: one 256-thread block per 32x32 tile. Thread (lg, lx) owns pixels
// (y0+lg+8k, x0+lx), k=0..3. Cells processed 8 at a time: threads cooperatively
// build separable factors ex[8][32] (conf folded in) and ey[8][32] in LDS,
// then FMA-accumulate via broadcast LDS reads.
__global__ __launch_bounds__(256) void pif_accum(const float4* __restrict__ cdata,
                                                 const int* __restrict__ counts,
                                                 const int* __restrict__ lists,
                                                 float* __restrict__ out,
                                                 int cap) {
    int tx = blockIdx.x, ty = blockIdx.y, b = blockIdx.z;
    int tid = threadIdx.x;
    int lx = tid & 31;        // column within tile (also used as row index i
    int lg = tid >> 5;        // 0..7           when building the ey table)

    __shared__ float4 cellLDS[256];
    __shared__ float  exL[8][32];
    __shared__ float  eyL[8][32];

    int tileId = (b * TYN + ty) * TXN + tx;
    int count = counts[tileId];
    if (count > cap) count = cap;
    const int* list = lists + (size_t)tileId * cap;

    float x0 = (float)(tx * TS);
    float y0 = (float)(ty * TS);

    float acc0 = 0.f, acc1 = 0.f, acc2 = 0.f, acc3 = 0.f;

    for (int base = 0; base < count; base += 256) {
        int n = count - base;
        if (n > 256) n = 256;
        // stage this chunk's cell data into LDS (zero-pad the tail: cf=0 -> ex=0)
        if (tid < n) {
            cellLDS[tid] = cdata[(size_t)b * J_ + list[base + tid]];
        } else {
            cellLDS[tid] = make_float4(0.f, 0.f, 0.f, 0.f);
        }
        __syncthreads();

        int nsub = (n + 7) >> 3;
        for (int s = 0; s < nsub; ++s) {
            // build separable factors for cells [8s, 8s+8): thread computes
            // cell c=lg, index i=lx for both the x-table and the y-table.
            float4 cd = cellLDS[s * 8 + lg];
            float dx = (x0 + (float)lx) - cd.x;
            float dy = (y0 + (float)lx) - cd.y;
            exL[lg][lx] = cd.w * __expf(-dx * dx * cd.z);
            eyL[lg][lx] = __expf(-dy * dy * cd.z);
            __syncthreads();

            #pragma unroll
            for (int c = 0; c < 8; ++c) {
                float exv = exL[c][lx];
                float e0 = eyL[c][lg];
                float e1 = eyL[c][lg + 8];
                float e2 = eyL[c][lg + 16];
                float e3 = eyL[c][lg + 24];
                acc0 = fmaf(e0, exv, acc0);
                acc1 = fmaf(e1, exv, acc1);
                acc2 = fmaf(e2, exv, acc2);
                acc3 = fmaf(e3, exv, acc3);
            }
            __syncthreads();
        }
    }

    int xo = tx * TS + lx;
    int yo = ty * TS + lg;
    size_t o = ((size_t)(b * HF + yo)) * WF + xo;
    out[o]            = acc0;
    out[o +  8 * WF]  = acc1;
    out[o + 16 * WF]  = acc2;
    out[o + 24 * WF]  = acc3;
}

extern "C" void kernel_launch(void* const* d_in, const int* in_sizes, int n_in,
                              void* d_out, int out_size, void* d_ws, size_t ws_size,
                              hipStream_t stream) {
    const float* mean = (const float*)d_in[0];
    const float* var  = (const float*)d_in[1];
    const float* conf = (const float*)d_in[2];
    float* out = (float*)d_out;

    char* ws = (char*)d_ws;
    float4* cdata = (float4*)ws;
    int* counts   = (int*)(ws + CDATA_BYTES);
    int* lists    = (int*)(ws + CDATA_BYTES + COUNT_BYTES);

    size_t fixed = (size_t)CDATA_BYTES + COUNT_BYTES;
    size_t avail = (ws_size > fixed) ? (ws_size - fixed) : 0;
    size_t cap_s = avail / ((size_t)NTILE * 4);
    int cap = (cap_s > CAPMAX) ? CAPMAX : (int)cap_s;
    if (cap < 1) cap = 1;  // degenerate ws; nothing better we can do

    pif_zero<<<(NTILE + 255) / 256, 256, 0, stream>>>(counts);

    int nthreads = B_ * J_;
    pif_bin<<<(nthreads + 255) / 256, 256, 0, stream>>>(mean, var, conf,
                                                        cdata, counts, lists, cap);

    pif_accum<<<dim3(TXN, TYN, B_), 256, 0, stream>>>(cdata, counts, lists, out, cap);
}

// Round 3
// 57.613 us; speedup vs baseline: 1.0163x; 1.0163x over previous
//
#include <hip/hip_runtime.h>

#define B_ 4
#define H_ 68
#define W_ 120
#define J_ (H_*W_)            // 8160 cells per batch
#define HF 544
#define WF 960
#define TS 32
#define TXN (WF/TS)           // 30
#define TYN (HF/TS)           // 17
#define NTILE (B_*TXN*TYN)    // 2040
#define CAPMAX 512

#define CDATA_BYTES (B_*J_*16)
#define COUNT_BYTES (NTILE*4)

typedef _Float16 half8 __attribute__((ext_vector_type(8)));
typedef float floatx16 __attribute__((ext_vector_type(16)));

// Phase 0: zero per-tile counters (hipMemsetAsync as a graph fill node was a
// red herring in R1, but a kernel is still the cheapest correct option).
__global__ __launch_bounds__(256) void pif_zero(int* __restrict__ counts) {
    int i = blockIdx.x * 256 + threadIdx.x;
    if (i < NTILE) counts[i] = 0;
}

// Phase 1: per-cell binning. Each active cell appends its index to all tiles
// within its truncation radius r = sqrt(2*var*ln(conf*1e5)).
__global__ __launch_bounds__(256) void pif_bin(const float* __restrict__ mean,
                                               const float* __restrict__ var,
                                               const float* __restrict__ conf,
                                               float4* __restrict__ cdata,
                                               int* __restrict__ counts,
                                               int* __restrict__ lists,
                                               int cap) {
    int gid = blockIdx.x * 256 + threadIdx.x;
    if (gid >= B_ * J_) return;
    int b = gid / J_;
    int j = gid - b * J_;

    float mx = mean[2 * gid + 0];
    float my = mean[2 * gid + 1];
    float v  = var[gid];
    float cf = conf[gid];
    float iv = 1.0f / (2.0f * v);
    cdata[gid] = make_float4(mx, my, iv, cf);

    if (!(cf > 0.1f)) return;   // thresholded cells contribute exactly 0

    // cut where conf*exp(-d^2 * iv) < 1e-5  ->  d^2 > 2*var*ln(conf*1e5)
    float lc = __logf(cf * 1e5f);           // conf>0.1 -> lc in [9.2, 11.5]
    float r  = sqrtf(fmaxf(2.0f * v * lc, 0.0f));

    int tx0 = max(0,       (int)floorf((mx - r) * (1.0f / TS)));
    int tx1 = min(TXN - 1, (int)floorf((mx + r) * (1.0f / TS)));
    int ty0 = max(0,       (int)floorf((my - r) * (1.0f / TS)));
    int ty1 = min(TYN - 1, (int)floorf((my + r) * (1.0f / TS)));

    for (int ty = ty0; ty <= ty1; ++ty) {
        for (int tx = tx0; tx <= tx1; ++tx) {
            int t = (b * TYN + ty) * TXN + tx;
            int idx = atomicAdd(&counts[t], 1);
            if (idx < cap) lists[(size_t)t * cap + idx] = j;
        }
    }
}

// Phase 2 (MFMA): one WAVE per 32x32 tile; rank-1 updates acc += ey(c) ⊗ ex(c)
// batched 16 cells per v_mfma_f32_32x32x16_f16. Lane layout:
//   lx = lane&31 is BOTH the A-row (y) this lane computes ey for and the
//   B-col (x) it computes ex for; half = lane>>5 selects which 8 of the 16
//   k-slots this lane fills. Cell->k-slot assignment is identical for A and B,
//   so any bijective hardware k ordering yields the same sum.
// C/D layout (verified, learn_hip m74/m101): col=lane&31,
//   row=(reg&3)+8*(reg>>2)+4*(lane>>5).
__global__ __launch_bounds__(256) void pif_accum_mfma(const float4* __restrict__ cdata,
                                                      const int* __restrict__ counts,
                                                      const int* __restrict__ lists,
                                                      float* __restrict__ out,
                                                      int cap) {
    int wid  = threadIdx.x >> 6;          // wave within block, 0..3
    int lane = threadIdx.x & 63;
    int tile = blockIdx.x * 4 + wid;      // grid = NTILE/4 blocks (2040/4=510)
    if (tile >= NTILE) return;

    int b   = tile / (TYN * TXN);
    int rem = tile - b * (TYN * TXN);
    int ty  = rem / TXN;
    int tx  = rem - ty * TXN;

    int count = counts[tile];
    if (count > cap) count = cap;
    const int* list = lists + (size_t)tile * cap;
    const float4* cb = cdata + (size_t)b * J_;

    int lx   = lane & 31;
    int half = lane >> 5;
    float xf = (float)(tx * TS + lx);
    float yf = (float)(ty * TS + lx);

    floatx16 acc = {};

    for (int base = 0; base < count; base += 16) {
        half8 af, bf;
        // load the 8 cells this half-wave owns (uniform addr per half -> L1 broadcast)
        float4 cd[8];
        #pragma unroll
        for (int i = 0; i < 8; ++i) {
            int ci = base + 8 * half + i;
            cd[i] = (ci < count) ? cb[list[ci]] : make_float4(0.f, 0.f, 0.f, 0.f);
        }
        #pragma unroll
        for (int i = 0; i < 8; ++i) {
            float dy = yf - cd[i].y;
            float dx = xf - cd[i].x;
            float ey = __expf(-dy * dy * cd[i].z);
            float ex = cd[i].w * __expf(-dx * dx * cd[i].z);  // pad cells: w=0 -> ex=0
            af[i] = (_Float16)ey;
            bf[i] = (_Float16)ex;
        }
        acc = __builtin_amdgcn_mfma_f32_32x32x16_f16(af, bf, acc, 0, 0, 0);
    }

    int xo = tx * TS + lx;
    #pragma unroll
    for (int r = 0; r < 16; ++r) {
        int row = (r & 3) + 8 * (r >> 2) + 4 * half;
        int yo  = ty * TS + row;
        out[((size_t)(b * HF + yo)) * WF + xo] = acc[r];
    }
}

extern "C" void kernel_launch(void* const* d_in, const int* in_sizes, int n_in,
                              void* d_out, int out_size, void* d_ws, size_t ws_size,
                              hipStream_t stream) {
    const float* mean = (const float*)d_in[0];
    const float* var  = (const float*)d_in[1];
    const float* conf = (const float*)d_in[2];
    float* out = (float*)d_out;

    char* ws = (char*)d_ws;
    float4* cdata = (float4*)ws;
    int* counts   = (int*)(ws + CDATA_BYTES);
    int* lists    = (int*)(ws + CDATA_BYTES + COUNT_BYTES);

    size_t fixed = (size_t)CDATA_BYTES + COUNT_BYTES;
    size_t avail = (ws_size > fixed) ? (ws_size - fixed) : 0;
    size_t cap_s = avail / ((size_t)NTILE * 4);
    int cap = (cap_s > CAPMAX) ? CAPMAX : (int)cap_s;
    if (cap < 1) cap = 1;  // degenerate ws; nothing better we can do

    pif_zero<<<(NTILE + 255) / 256, 256, 0, stream>>>(counts);

    int nthreads = B_ * J_;
    pif_bin<<<(nthreads + 255) / 256, 256, 0, stream>>>(mean, var, conf,
                                                        cdata, counts, lists, cap);

    pif_accum_mfma<<<(NTILE + 3) / 4, 256, 0, stream>>>(cdata, counts, lists, out, cap);
}

// Round 4
// 46.594 us; speedup vs baseline: 1.2566x; 1.2365x over previous
//
#include <hip/hip_runtime.h>

#define B_ 4
#define H_ 68
#define W_ 120
#define J_ (H_*W_)            // 8160 cells per batch
#define HF 544
#define WF 960
#define TS 32
#define TXN (WF/TS)           // 30
#define TYN (HF/TS)           // 17
#define NTPB (TXN*TYN)        // 510 tiles per batch

typedef _Float16 half8 __attribute__((ext_vector_type(8)));
typedef float floatx16 __attribute__((ext_vector_type(16)));

// Single fused kernel: one WAVE per 32x32 output tile (4 waves/block).
// Phase A+B interleaved per 64-cell stripe:
//   scan: conservative circle-vs-tile test (d_clamped^2 <= 2*v*ln(1e5), conf>0.1),
//         ballot-compact survivor indices into a per-wave LDS queue;
//   drain: whenever >=16 queued, evaluate separable f16 fragments and issue one
//         v_mfma_f32_32x32x16_f16 rank-16 update (layout validated in R3:
//         cell -> same k-slot (half,i) in A and B; C/D row=(r&3)+8*(r>>2)+4*half).
// No workspace, no atomics, no __syncthreads, one dispatch.
__global__ __launch_bounds__(256) void pif_fused(const float2* __restrict__ mean,
                                                 const float*  __restrict__ var,
                                                 const float*  __restrict__ conf,
                                                 float* __restrict__ out) {
    __shared__ int queue[4][128];
    int wid  = threadIdx.x >> 6;
    int lane = threadIdx.x & 63;
    int tile = blockIdx.x * 4 + wid;
    int b    = blockIdx.y;
    if (tile >= NTPB) return;

    int ty = tile / TXN;
    int tx = tile - ty * TXN;

    const float2* mb = mean + (size_t)b * J_;
    const float*  vb = var  + (size_t)b * J_;
    const float*  cb = conf + (size_t)b * J_;

    float x0 = (float)(tx * TS), y0 = (float)(ty * TS);
    int   lx = lane & 31, half = lane >> 5;
    float xf = x0 + (float)lx;
    float yf = y0 + (float)lx;

    int* q  = queue[wid];
    int  qn = 0;
    floatx16 acc = {};

    for (int base = 0; base < J_; base += 64) {
        int j = base + lane;
        bool p = false;
        if (j < J_) {
            float2 m  = mb[j];
            float  v  = vb[j];
            float  cf = cb[j];
            float cx = fminf(fmaxf(m.x, x0), x0 + 31.f);
            float cy = fminf(fmaxf(m.y, y0), y0 + 31.f);
            float ddx = m.x - cx, ddy = m.y - cy;
            // keep if closest tile pixel is inside r^2 = 2*v*ln(1e5) >= per-cell cut
            p = (cf > 0.1f) & (ddx * ddx + ddy * ddy <= 23.03f * v);
        }
        unsigned long long mask = __ballot(p);
        if (p) {
            int pos = __popcll(mask & ((1ull << lane) - 1ull));
            q[qn + pos] = j;
        }
        qn += __popcll(mask);

        while (qn >= 16) {
            qn -= 16;
            const int* qq = q + qn;
            float4 cd[8];
            #pragma unroll
            for (int i = 0; i < 8; ++i) {
                int cidx = qq[8 * half + i];      // LDS broadcast per half-wave
                float2 m  = mb[cidx];
                float  v  = vb[cidx];
                float  cf = cb[cidx];
                cd[i] = make_float4(m.x, m.y, __builtin_amdgcn_rcpf(2.f * v), cf);
            }
            half8 af, bf;
            #pragma unroll
            for (int i = 0; i < 8; ++i) {
                float dy = yf - cd[i].y;
                float dx = xf - cd[i].x;
                af[i] = (_Float16)__expf(-dy * dy * cd[i].z);
                bf[i] = (_Float16)(cd[i].w * __expf(-dx * dx * cd[i].z));
            }
            acc = __builtin_amdgcn_mfma_f32_32x32x16_f16(af, bf, acc, 0, 0, 0);
        }
    }

    if (qn > 0) {                                  // padded tail chunk
        float4 cd[8];
        #pragma unroll
        for (int i = 0; i < 8; ++i) {
            int ci = 8 * half + i;
            if (ci < qn) {
                int cidx = q[ci];
                float2 m  = mb[cidx];
                float  v  = vb[cidx];
                float  cf = cb[cidx];
                cd[i] = make_float4(m.x, m.y, __builtin_amdgcn_rcpf(2.f * v), cf);
            } else {
                cd[i] = make_float4(0.f, 0.f, 0.f, 0.f);  // cf=0 -> bf=0 -> no contribution
            }
        }
        half8 af, bf;
        #pragma unroll
        for (int i = 0; i < 8; ++i) {
            float dy = yf - cd[i].y;
            float dx = xf - cd[i].x;
            af[i] = (_Float16)__expf(-dy * dy * cd[i].z);
            bf[i] = (_Float16)(cd[i].w * __expf(-dx * dx * cd[i].z));
        }
        acc = __builtin_amdgcn_mfma_f32_32x32x16_f16(af, bf, acc, 0, 0, 0);
    }

    int xo = tx * TS + lx;
    #pragma unroll
    for (int r = 0; r < 16; ++r) {
        int row = (r & 3) + 8 * (r >> 2) + 4 * half;
        int yo  = ty * TS + row;
        out[((size_t)(b * HF + yo)) * WF + xo] = acc[r];
    }
}

extern "C" void kernel_launch(void* const* d_in, const int* in_sizes, int n_in,
                              void* d_out, int out_size, void* d_ws, size_t ws_size,
                              hipStream_t stream) {
    const float2* mean = (const float2*)d_in[0];
    const float*  var  = (const float*)d_in[1];
    const float*  conf = (const float*)d_in[2];
    float* out = (float*)d_out;
    (void)d_ws; (void)ws_size;

    pif_fused<<<dim3((NTPB + 3) / 4, B_), 256, 0, stream>>>(mean, var, conf, out);
}

// Round 5
// 31.660 us; speedup vs baseline: 1.8493x; 1.4717x over previous
//
#include <hip/hip_runtime.h>

#define B_ 4
#define J_ 8160               // 68*120 cells per batch
#define HF 544
#define WF 960
#define TS 32
#define TXN 30
#define TYN 17
#define NTPB 510              // tiles per batch
#define R2COEF 23.0259f       // 2*ln(1e5): keep cell if clamped d^2 <= R2COEF*var

typedef _Float16 half8 __attribute__((ext_vector_type(8)));
typedef float floatx16 __attribute__((ext_vector_type(16)));

// Pack (mx, my, var, conf-masked) into one float4 so the scan does ONE load
// per cell instead of three.
__global__ __launch_bounds__(256) void pif_pack(const float2* __restrict__ mean,
                                                const float* __restrict__ var,
                                                const float* __restrict__ conf,
                                                float4* __restrict__ cdata) {
    int gid = blockIdx.x * 256 + threadIdx.x;
    if (gid >= B_ * J_) return;
    float2 m = mean[gid];
    float v  = var[gid];
    float cf = conf[gid];
    cdata[gid] = make_float4(m.x, m.y, v, cf > 0.1f ? cf : 0.0f);
}

// One BLOCK per 32x32 tile (2040 blocks, 8/CU co-resident). Wave w scans cells
// [w*2040, (w+1)*2040): prefetched float4 loads, ballot-compact survivors into
// a per-wave LDS queue (region of `red`, dead by reduce time), drain 16 at a
// time into v_mfma_f32_32x32x16_f16 partial accumulators (layout validated
// R3/R4: cell -> same k-slot (half,i) in A and B; C/D row=(r&3)+8*(r>>2)+4*half).
// Final: LDS reduce of the 4 partial tiles.
__global__ __launch_bounds__(256, 8) void pif_tile(const float4* __restrict__ cdata,
                                                   float* __restrict__ out) {
    __shared__ float red[4][32][32];   // per-wave queue first, then partial tiles
    int wid  = threadIdx.x >> 6;
    int lane = threadIdx.x & 63;
    int tile = blockIdx.x;
    int b    = blockIdx.y;

    int ty = tile / TXN;
    int tx = tile - ty * TXN;

    const float4* cb = cdata + (size_t)b * J_;
    int* q  = (int*)&red[wid][0][0];   // 1024 ints per wave
    int  qn = 0;

    float x0 = (float)(tx * TS), y0 = (float)(ty * TS);
    int   lx = lane & 31, half = lane >> 5;
    float xf = x0 + (float)lx;
    float yf = y0 + (float)lx;

    floatx16 acc = {};

    auto drain16 = [&](const int* qq) {
        half8 af, bf;
        #pragma unroll
        for (int i = 0; i < 8; ++i) {
            int cidx = qq[8 * half + i];           // LDS broadcast per half-wave
            float4 cd = cb[cidx];                  // broadcast global load
            float iv = __builtin_amdgcn_rcpf(2.0f * cd.z);
            float dy = yf - cd.y;
            float dx = xf - cd.x;
            af[i] = (_Float16)__expf(-dy * dy * iv);
            bf[i] = (_Float16)(cd.w * __expf(-dx * dx * iv));
        }
        acc = __builtin_amdgcn_mfma_f32_32x32x16_f16(af, bf, acc, 0, 0, 0);
    };

    const int slice = J_ / 4;                      // 2040
    int jbeg = wid * slice, jend = jbeg + slice;

    float4 nxt = cb[jbeg + lane];                  // jbeg+63 <= 6183 < J_
    for (int base = jbeg; base < jend; base += 64) {
        float4 cur = nxt;
        int pj = base + 64 + lane;
        nxt = cb[pj < J_ ? pj : 0];                // prefetch next stripe
        int j = base + lane;

        float cx = fminf(fmaxf(cur.x, x0), x0 + 31.f);
        float cy = fminf(fmaxf(cur.y, y0), y0 + 31.f);
        float ddx = cur.x - cx, ddy = cur.y - cy;
        bool p = (j < jend) & (cur.w > 0.0f) &
                 (ddx * ddx + ddy * ddy <= R2COEF * cur.z);

        unsigned long long mask = __ballot(p);
        if (p) {
            int pos = __popcll(mask & ((1ull << lane) - 1ull));
            q[qn + pos] = j;
        }
        qn += __popcll(mask);                      // qn <= 943+64 = 1007 < 1024

        if (__builtin_expect(qn >= 944, 0)) {      // cold: only adversarial data
            while (qn >= 16) { qn -= 16; drain16(q + qn); }
        }
    }

    while (qn >= 16) { qn -= 16; drain16(q + qn); }
    if (qn > 0) {                                  // padded tail chunk
        half8 af, bf;
        #pragma unroll
        for (int i = 0; i < 8; ++i) {
            int ci = 8 * half + i;
            float4 cd = (ci < qn) ? cb[q[ci]] : make_float4(0.f, 0.f, 1.f, 0.f);
            float iv = __builtin_amdgcn_rcpf(2.0f * cd.z);
            float dy = yf - cd.y;
            float dx = xf - cd.x;
            af[i] = (_Float16)__expf(-dy * dy * iv);
            bf[i] = (_Float16)(cd.w * __expf(-dx * dx * iv));  // w=0 -> 0 contribution
        }
        acc = __builtin_amdgcn_mfma_f32_32x32x16_f16(af, bf, acc, 0, 0, 0);
    }

    // queue regions are dead from here; reuse red[] for the 4 partial tiles
    __syncthreads();
    #pragma unroll
    for (int r = 0; r < 16; ++r) {
        int row = (r & 3) + 8 * (r >> 2) + 4 * half;
        red[wid][row][lx] = acc[r];                // 2-way bank alias: free
    }
    __syncthreads();

    int t = threadIdx.x;
    #pragma unroll
    for (int k = 0; k < 4; ++k) {
        int p   = t + 256 * k;
        int row = p >> 5, col = p & 31;
        float s = red[0][row][col] + red[1][row][col]
                + red[2][row][col] + red[3][row][col];
        out[((size_t)(b * HF + ty * TS + row)) * WF + (tx * TS + col)] = s;
    }
}

extern "C" void kernel_launch(void* const* d_in, const int* in_sizes, int n_in,
                              void* d_out, int out_size, void* d_ws, size_t ws_size,
                              hipStream_t stream) {
    const float2* mean = (const float2*)d_in[0];
    const float*  var  = (const float*)d_in[1];
    const float*  conf = (const float*)d_in[2];
    float* out = (float*)d_out;

    float4* cdata = (float4*)d_ws;                 // 522,240 B

    pif_pack<<<(B_ * J_ + 255) / 256, 256, 0, stream>>>(mean, var, conf, cdata);
    pif_tile<<<dim3(NTPB, B_), 256, 0, stream>>>(cdata, out);
}

// Round 6
// 25.974 us; speedup vs baseline: 2.2542x; 1.2189x over previous
//
#include <hip/hip_runtime.h>
#include <hip/hip_fp16.h>

#define B_ 4
#define J_ 8160               // 68*120 cells per batch
#define JP_ 8192              // padded per-batch cell count (4 waves x 2048)
#define HF 544
#define WF 960
#define TS 32
#define TXN 30
#define TYN 17
#define NTPB 510              // tiles per batch
#define R2COEF 23.0259f       // 2*ln(1e5)

typedef _Float16 half8 __attribute__((ext_vector_type(8)));
typedef float floatx16 __attribute__((ext_vector_type(16)));

// ws layout:
//   float4 cdata[B_*J_]   (mx, my, 1/(2v), conf-masked)      522,240 B
//   uint2  scanh[B_*JP_]  ([hx, hy, hr, pad] f16; hr=r+17;   262,144 B
//                          hr=-1000 for dead/pad cells)

// Pack: full-precision drain record + 8-byte f16 scan record.
__global__ __launch_bounds__(256) void pif_pack(const float2* __restrict__ mean,
                                                const float* __restrict__ var,
                                                const float* __restrict__ conf,
                                                float4* __restrict__ cdata,
                                                uint2* __restrict__ scanh) {
    int gid = blockIdx.x * 256 + threadIdx.x;        // 0 .. B_*JP_-1
    if (gid >= B_ * JP_) return;
    int b  = gid >> 13;                               // /8192
    int jp = gid & (JP_ - 1);

    __half2 xy; __half hr;
    if (jp < J_) {
        int src = b * J_ + jp;
        float2 m = mean[src];
        float v  = var[src];
        float cf = conf[src];
        float iv = 1.0f / (2.0f * v);
        cdata[src] = make_float4(m.x, m.y, iv, cf > 0.1f ? cf : 0.0f);
        float r = sqrtf(R2COEF * v);
        xy = __floats2half2_rn(m.x, m.y);
        // +17 = 15.5 (tile half-width) + 1.5 slack (f16 coord/rounding error <=1)
        hr = __float2half(cf > 0.1f ? (r + 17.0f) : -1000.0f);
    } else {
        xy = __floats2half2_rn(0.f, 0.f);
        hr = __float2half(-1000.0f);                  // pad: never passes
    }
    uint2 w;
    w.x = *reinterpret_cast<unsigned int*>(&xy);
    unsigned short rb = *reinterpret_cast<unsigned short*>(&hr);
    w.y = (unsigned int)rb;
    scanh[gid] = w;
}

// One BLOCK per 32x32 tile (2040 blocks, ~8/CU). Wave w scans padded cells
// [w*2048, (w+1)*2048), 2 cells/lane/iter (16B load), f16 box test vs tile
// center, ballot-compact survivors into per-wave LDS queue, drain 16 at a
// time into v_mfma_f32_32x32x16_f16 (layout validated R3-R5).
__global__ __launch_bounds__(256, 8) void pif_tile(const float4* __restrict__ cdata,
                                                   const uint4* __restrict__ scanh2,
                                                   float* __restrict__ out) {
    __shared__ float red[4][32][32];   // per-wave queue first, then partial tiles
    int wid  = threadIdx.x >> 6;
    int lane = threadIdx.x & 63;
    int tile = blockIdx.x;
    int b    = blockIdx.y;

    int ty = tile / TXN;
    int tx = tile - ty * TXN;

    const float4* cb = cdata + (size_t)b * J_;
    int* q  = (int*)&red[wid][0][0];   // 1024 ints per wave
    int  qn = 0;

    float x0 = (float)(tx * TS), y0 = (float)(ty * TS);
    int   lx = lane & 31, half = lane >> 5;
    float xf = x0 + (float)lx;
    float yf = y0 + (float)lx;

    const __half2 ctr = __floats2half2_rn(x0 + 15.5f, y0 + 15.5f);
    const unsigned long long below = (1ull << lane) - 1ull;

    floatx16 acc = {};

    auto drain16 = [&](const int* qq) {
        half8 af, bf;
        #pragma unroll
        for (int i = 0; i < 8; ++i) {
            int cidx = qq[8 * half + i];           // LDS broadcast per half-wave
            float4 cd = cb[cidx];                  // broadcast global load (L1/L2)
            float dy = yf - cd.y;
            float dx = xf - cd.x;
            af[i] = (_Float16)__expf(-dy * dy * cd.z);
            bf[i] = (_Float16)(cd.w * __expf(-dx * dx * cd.z));
        }
        acc = __builtin_amdgcn_mfma_f32_32x32x16_f16(af, bf, acc, 0, 0, 0);
    };

    // this wave's padded slice: 2048 cells = 16 iters x (64 lanes x 2 cells)
    const uint4* sp = scanh2 + ((size_t)b * JP_ + wid * 2048) / 2;
    int jbase = wid * 2048;

    for (int s = 0; s < 16; ++s) {
        uint4 w = sp[s * 64 + lane];               // 2 scan records
        int j0 = jbase + s * 128 + 2 * lane;

        __half2 xy0 = *reinterpret_cast<__half2*>(&w.x);
        __half  r0  = *reinterpret_cast<__half*>(&w.y);
        __half2 xy1 = *reinterpret_cast<__half2*>(&w.z);
        __half  r1  = *reinterpret_cast<__half*>(&w.w);

        __half2 t0 = __hsub2(__habs2(__hsub2(xy0, ctr)), __halves2half2(r0, r0));
        __half2 t1 = __hsub2(__habs2(__hsub2(xy1, ctr)), __halves2half2(r1, r1));
        bool p0 = fmaxf(__low2float(t0), __high2float(t0)) <= 0.0f;
        bool p1 = fmaxf(__low2float(t1), __high2float(t1)) <= 0.0f;

        unsigned long long m0 = __ballot(p0);
        if (p0) q[qn + __popcll(m0 & below)] = j0;
        qn += __popcll(m0);
        unsigned long long m1 = __ballot(p1);
        if (p1) q[qn + __popcll(m1 & below)] = j0 + 1;
        qn += __popcll(m1);                        // qn <= 895 + 128 = 1023

        if (__builtin_expect(qn >= 896, 0)) {      // cold: adversarial data only
            while (qn >= 16) { qn -= 16; drain16(q + qn); }
        }
    }

    while (qn >= 16) { qn -= 16; drain16(q + qn); }
    if (qn > 0) {                                  // padded tail chunk
        half8 af, bf;
        #pragma unroll
        for (int i = 0; i < 8; ++i) {
            int ci = 8 * half + i;
            float4 cd = (ci < qn) ? cb[q[ci]] : make_float4(0.f, 0.f, 1.f, 0.f);
            float dy = yf - cd.y;
            float dx = xf - cd.x;
            af[i] = (_Float16)__expf(-dy * dy * cd.z);
            bf[i] = (_Float16)(cd.w * __expf(-dx * dx * cd.z));  // w=0 -> no contribution
        }
        acc = __builtin_amdgcn_mfma_f32_32x32x16_f16(af, bf, acc, 0, 0, 0);
    }

    // queue regions dead from here; reuse red[] for the 4 partial tiles
    __syncthreads();
    #pragma unroll
    for (int r = 0; r < 16; ++r) {
        int row = (r & 3) + 8 * (r >> 2) + 4 * half;
        red[wid][row][lx] = acc[r];                // 2-way bank alias: free
    }
    __syncthreads();

    int t = threadIdx.x;
    #pragma unroll
    for (int k = 0; k < 4; ++k) {
        int p   = t + 256 * k;
        int row = p >> 5, col = p & 31;
        float s = red[0][row][col] + red[1][row][col]
                + red[2][row][col] + red[3][row][col];
        out[((size_t)(b * HF + ty * TS + row)) * WF + (tx * TS + col)] = s;
    }
}

extern "C" void kernel_launch(void* const* d_in, const int* in_sizes, int n_in,
                              void* d_out, int out_size, void* d_ws, size_t ws_size,
                              hipStream_t stream) {
    const float2* mean = (const float2*)d_in[0];
    const float*  var  = (const float*)d_in[1];
    const float*  conf = (const float*)d_in[2];
    float* out = (float*)d_out;

    char* ws = (char*)d_ws;
    float4* cdata = (float4*)ws;                         // 522,240 B
    uint2*  scanh = (uint2*)(ws + (size_t)B_ * J_ * 16); // 262,144 B

    pif_pack<<<(B_ * JP_ + 255) / 256, 256, 0, stream>>>(mean, var, conf,
                                                         cdata, scanh);
    pif_tile<<<dim3(NTPB, B_), 256, 0, stream>>>(cdata, (const uint4*)scanh, out);
}